// Round 22
// baseline (150.597 us; speedup 1.0000x reference)
//
#include <hip/hip_runtime.h>

#define DEV __device__ __forceinline__

typedef float f32x4 __attribute__((ext_vector_type(4)));
typedef short short4v __attribute__((ext_vector_type(4)));
typedef short short8v __attribute__((ext_vector_type(8)));
typedef __bf16 bf16x8 __attribute__((ext_vector_type(8)));

#define PSTR  (2048L * 2048)
#define OSTR  (2048L * 1024)

DEV unsigned short f2bf(float f) {
  unsigned int u = __float_as_uint(f);
  u += 0x7fffu + ((u >> 16) & 1u);   // round-to-nearest-even
  return (unsigned short)(u >> 16);
}
DEV float bf2f(short s) {
  return __uint_as_float(((unsigned int)(unsigned short)s) << 16);
}

DEV void async16(void* lds, const void* g) {
  __builtin_amdgcn_global_load_lds((const __attribute__((address_space(1))) void*)g,
                                   (__attribute__((address_space(3))) void*)lds, 16, 0, 0);
}

DEV float wave_red(float v) {
#pragma unroll
  for (int o = 1; o < 64; o <<= 1) v += __shfl_xor(v, o);
  return v;
}

// ---------------- prologue: casts, Wv transpose, g/h/c ----------------
__global__ void pre_kernel(const float* __restrict__ x, short* __restrict__ xb,
                           const float* __restrict__ Wq, const float* __restrict__ Wk,
                           const float* __restrict__ Wv,
                           short* __restrict__ wqb, short* __restrict__ wkb,
                           short* __restrict__ wvt,
                           const float* __restrict__ bq, const float* __restrict__ bk,
                           float* __restrict__ g, float* __restrict__ h,
                           float* __restrict__ cbuf)
{
  __shared__ float t[32][33];
  const int b = blockIdx.x;
  const int tid = threadIdx.x;
  if (b < 4096) {                    // cast x -> bf16, 8 elems/thread
    long i = ((long)b * 256 + tid) * 8;
    f32x4 a = *(const f32x4*)(x + i);
    f32x4 c2 = *(const f32x4*)(x + i + 4);
    short8v o;
#pragma unroll
    for (int j = 0; j < 4; ++j) { o[j] = (short)f2bf(a[j]); o[4 + j] = (short)f2bf(c2[j]); }
    *(short8v*)(xb + i) = o;
  } else if (b < 5120) {             // straight cast Wq / Wk -> bf16
    int tb = b - 4096;
    const float* W = (tb < 512) ? Wq : Wk;
    short* Wo = (tb < 512) ? wqb : wkb;
    long i = ((long)(tb & 511) * 256 + tid) * 8;
    f32x4 a = *(const f32x4*)(W + i);
    f32x4 c2 = *(const f32x4*)(W + i + 4);
    short8v o;
#pragma unroll
    for (int j = 0; j < 4; ++j) { o[j] = (short)f2bf(a[j]); o[4 + j] = (short)f2bf(c2[j]); }
    *(short8v*)(Wo + i) = o;
  } else if (b < 6144) {             // transpose+cast one 32x32 tile of Wv
    int t2 = b - 5120;
    int n0 = (t2 & 31) * 32, k0 = (t2 >> 5) * 32;
    int tx = tid & 31, ty = tid >> 5;
#pragma unroll
    for (int r = 0; r < 32; r += 8) t[ty + r][tx] = Wv[(long)(k0 + ty + r) * 1024 + n0 + tx];
    __syncthreads();
#pragma unroll
    for (int r = 0; r < 32; r += 8)
      wvt[(long)(n0 + ty + r) * 1024 + k0 + tx] = (short)f2bf(t[tx][ty + r]);
  } else if (b < 6656) {             // g (256 blocks) then h (256 blocks)
    int local = b - 6144;
    const float* W = (local < 256) ? Wq : Wk;
    const float* bb = (local < 256) ? bk : bq;
    float* out = (local < 256) ? g : h;
    const int d = (local & 255) * 4 + (tid >> 6);
    const int lane = tid & 63;
    const float* row = W + (long)d * 1024 + lane * 16;
    const float* bp = bb + lane * 16;
    float s = 0.f;
#pragma unroll
    for (int q = 0; q < 4; ++q) {
      f32x4 wv = *(const f32x4*)(row + q * 4);
      f32x4 bv2 = *(const f32x4*)(bp + q * 4);
#pragma unroll
      for (int j = 0; j < 4; ++j) s += wv[j] * bv2[j];
    }
    s = wave_red(s);
    if (lane == 0) out[d] = s;
  } else {                           // c = bq . bk
    float s = 0.f;
#pragma unroll
    for (int q = 0; q < 4; ++q) s += bq[tid + q * 256] * bk[tid + q * 256];
    s = wave_red(s);
    __shared__ float red[4];
    if ((tid & 63) == 0) red[tid >> 6] = s;
    __syncthreads();
    if (tid == 0) cbuf[0] = red[0] + red[1] + red[2] + red[3];
  }
}

// ================= BK=64 body (all GEMMs; grids run ~2 blocks/CU) =================
// 64KB LDS: As0|As1|Bs0|Bs1, each 8192 shorts ([128 rows][64 cols] bf16).
// Staging: 16 chunks of 8 rows; lane l -> row l>>3, source col-slot
// (l&7)^(l>>3). Reads XOR the same involution -> 2-way bank aliasing (free).
// MODE 0: bf16 out, LDS-bounce, optional row bias (bias_m).
// MODE 1: scores (P_un + column sums + u/w bias). MODE 2: PV (K cap, f32 out).
template <typename CT, int MODE>
DEV void gemm_body64(short* lds,
                     const short* A, const short* Bt, CT* C,
                     int K, int lda, int ldbt, int ldc,
                     float scale, const float* bias_m,
                     const float* u_vec, const float* w_vec,
                     float* ps_out, int bn, int bm, int bz)
{
  short* As0 = lds;
  short* As1 = lds + 8192;
  short* Bs0 = lds + 16384;
  short* Bs1 = lds + 24576;
  const int kend = (MODE == 2) ? min(K, (bm + 1) * 128) : K;

  const int tid = threadIdx.x;
  const int wid = tid >> 6, lane = tid & 63;
  const int wm = wid >> 1, wn = wid & 1;
  const int lrow = lane >> 3;                      // row within 8-row chunk
  const int lcol = ((lane & 7) ^ lrow) * 8;        // inverse-swizzled source slot
  const int fr = lane & 15;
  const int fq = lane >> 4;

  const short* Ab = A + (long)(bm * 128 + lrow) * lda + lcol;
  const short* Bb = Bt + (long)(bn * 128 + lrow) * ldbt + lcol;

  f32x4 acc[4][4] = {};

  auto STAGE = [&](short* Asb, short* Bsb, int kk) {
#pragma unroll
    for (int j = 0; j < 4; ++j) {
      int chunk = j * 4 + wid;                     // 0..15 (8 rows each)
      async16(&Asb[chunk * 512], Ab + (long)chunk * 8 * lda + kk);
      async16(&Bsb[chunk * 512], Bb + (long)chunk * 8 * ldbt + kk);
    }
  };

  STAGE(As0, Bs0, 0);
  int cur = 0;
  for (int kk = 0; kk < kend; kk += 64) {
    const short* Ac = cur ? As1 : As0;
    const short* Bc = cur ? Bs1 : Bs0;
    if (kk + 64 < kend) {
      STAGE(cur ? As0 : As1, cur ? Bs0 : Bs1, kk + 64);
      asm volatile("s_waitcnt vmcnt(8)" ::: "memory");
    } else {
      asm volatile("s_waitcnt vmcnt(0)" ::: "memory");
    }
    __builtin_amdgcn_s_barrier();
    __builtin_amdgcn_sched_barrier(0);

#pragma unroll
    for (int s = 0; s < 2; ++s) {
      bf16x8 af[4], bf_[4];
#pragma unroll
      for (int i = 0; i < 4; ++i) {
        int row = wm * 64 + i * 16 + fr;
        af[i] = *(const bf16x8*)((const char*)Ac + row * 128 +
                                 (((s * 4 + fq) ^ (fr & 7)) * 16));
      }
#pragma unroll
      for (int j = 0; j < 4; ++j) {
        int row = wn * 64 + j * 16 + fr;
        bf_[j] = *(const bf16x8*)((const char*)Bc + row * 128 +
                                  (((s * 4 + fq) ^ (fr & 7)) * 16));
      }
#pragma unroll
      for (int i = 0; i < 4; ++i)
#pragma unroll
        for (int j = 0; j < 4; ++j)
          acc[i][j] = __builtin_amdgcn_mfma_f32_16x16x32_bf16(af[i], bf_[j], acc[i][j], 0, 0, 0);
    }
    __builtin_amdgcn_s_barrier();
    cur ^= 1;
  }

  const int rl0 = wm * 64 + fq * 4;        // local row base (i stride 16)
  const int cl0 = wn * 64 + fr;            // local col base (j stride 16)

  if constexpr (MODE == 2) {
#pragma unroll
    for (int i = 0; i < 4; ++i) {
#pragma unroll
      for (int r = 0; r < 4; ++r) {
        int row = bm * 128 + rl0 + i * 16 + r;
#pragma unroll
        for (int j = 0; j < 4; ++j) {
          int col = bn * 128 + cl0 + j * 16;
          C[(long)row * ldc + col] = acc[i][j][r] * scale;
        }
      }
    }
  } else {
    // -------- LDS-bounce epilogue (bf16 tile), pt spans As0|As1 --------
    short* pt = lds;                       // 16384 shorts = 128x128 tile
    if constexpr (MODE == 0) {
#pragma unroll
      for (int i = 0; i < 4; ++i) {
#pragma unroll
        for (int r = 0; r < 4; ++r) {
          int rl = rl0 + i * 16 + r;
          float bmv = bias_m ? bias_m[bm * 128 + rl] : 0.f;
#pragma unroll
          for (int j = 0; j < 4; ++j) {
            int cl = cl0 + j * 16;
            pt[rl * 128 + cl] = (short)f2bf(acc[i][j][r] * scale + bmv);
          }
        }
      }
    } else {
      float uu[4][4];
#pragma unroll
      for (int i = 0; i < 4; ++i)
#pragma unroll
        for (int r = 0; r < 4; ++r) uu[i][r] = u_vec[bm * 128 + rl0 + i * 16 + r];
#pragma unroll
      for (int j = 0; j < 4; ++j) {
        const int cl = cl0 + j * 16;
        const int col = bn * 128 + cl;
        const float wc = w_vec[col];
#pragma unroll
        for (int i = 0; i < 4; ++i)
#pragma unroll
          for (int r = 0; r < 4; ++r) {
            int rl = rl0 + i * 16 + r;
            int row = bm * 128 + rl;
            float e = (row >= col) ? __expf((acc[i][j][r] + uu[i][r] + wc) * scale) : 0.f;
            pt[rl * 128 + cl] = (short)f2bf(e);
          }
      }
    }
    __syncthreads();
    if constexpr (MODE == 1) {
      if (tid < 128) {
        float s = 0.f;
#pragma unroll 8
        for (int r2 = 0; r2 < 128; ++r2) s += bf2f(pt[r2 * 128 + tid]);
        ps_out[((long)bz * 16 + bm) * 2048 + bn * 128 + tid] = s;
      }
    }
    const long cbase = (long)bm * 128 * ldc + bn * 128;
#pragma unroll
    for (int p2 = 0; p2 < 8; ++p2) {
      int flat = p2 * 2048 + tid * 8;
      int rl = flat >> 7, cl = flat & 127;
      *(short8v*)((short*)C + cbase + (long)rl * ldc + cl) = *(const short8v*)(pt + flat);
    }
  }
}

// aux64 (576 = 8*72, BK=64): per XCD k: 64 Vt tiles (slice-owned: bn in
// [8k,8k+8), bias bv over rows=d) + 8 M-tiles (Mt = Wk.Wq^T).
__global__ __launch_bounds__(256, 2) void aux64(
    const short* __restrict__ wqb, const short* __restrict__ wkb,
    short* __restrict__ Mt,
    const short* __restrict__ xb, const short* __restrict__ wvt,
    const float* __restrict__ bv, short* __restrict__ vt)
{
  __shared__ __align__(16) short lds[32768];
  int b = (int)blockIdx.x;
  const int k = b & 7;                           // XCD
  const int j = b >> 3;                          // [0,72)
  if (j < 64) {
    const int bn = k * 8 + (j & 7);              // Vt tile, slice-owned
    const int bm = j >> 3;
    gemm_body64<short, 0>(lds, wvt, xb, vt, 1024, 1024, 1024, 8192,
                          1.f, bv, nullptr, nullptr, nullptr, bn, bm, 0);
  } else {
    const int id = k * 8 + (j - 64);             // M tile
    gemm_body64<short, 0>(lds, wkb, wqb, Mt, 1024, 1024, 1024, 1024,
                          1.f, nullptr, nullptr, nullptr, nullptr, id & 7, id >> 3, 0);
  }
}

// yuw (2560 = 8*320, BK=64): per XCD k: 64 ygemm tiles (slice-owned: bm in
// [8k,8k+8)) + 256 u/w blocks (4 wave-rows each): u[s]=xb[s].g+c, w[s]=xb[s].h.
__global__ __launch_bounds__(256, 2) void yuw(
    const short* __restrict__ xb, const short* __restrict__ Mt,
    short* __restrict__ y,
    const float* __restrict__ g, const float* __restrict__ h,
    const float* __restrict__ cbuf,
    float* __restrict__ u, float* __restrict__ w)
{
  __shared__ __align__(16) short lds[32768];
  int b = (int)blockIdx.x;
  const int k = b & 7;                           // XCD
  const int j = b >> 3;                          // [0,320)
  if (j < 64) {
    const int bn = j >> 3;
    const int bm = k * 8 + (j & 7);              // slice-owned
    gemm_body64<short, 0>(lds, xb, Mt, y, 1024, 1024, 1024, 1024,
                          1.f, nullptr, nullptr, nullptr, nullptr, bn, bm, 0);
  } else {
    const int id = k * 256 + (j - 64);           // u/w: 4 rows (1 per wave)
    const int wv_ = threadIdx.x >> 6, lane = threadIdx.x & 63;
    const int s = id * 4 + wv_;
    const short* row = xb + (long)s * 1024 + lane * 16;
    const float* gp = g + lane * 16;
    const float* hp = h + lane * 16;
    short8v xa = *(const short8v*)(row);
    short8v xb2 = *(const short8v*)(row + 8);
    float du = 0.f, dw = 0.f;
#pragma unroll
    for (int q = 0; q < 2; ++q) {
      f32x4 ga = *(const f32x4*)(gp + q * 4);
      f32x4 gb = *(const f32x4*)(gp + 8 + q * 4);
      f32x4 ha = *(const f32x4*)(hp + q * 4);
      f32x4 hb = *(const f32x4*)(hp + 8 + q * 4);
#pragma unroll
      for (int i2 = 0; i2 < 4; ++i2) {
        float xv0 = bf2f(xa[q * 4 + i2]);
        float xv1 = bf2f(xb2[q * 4 + i2]);
        du += xv0 * ga[i2] + xv1 * gb[i2];
        dw += xv0 * ha[i2] + xv1 * hb[i2];
      }
    }
    du = wave_red(du);
    dw = wave_red(dw);
    if (lane == 0) { u[s] = du + cbuf[0]; w[s] = dw; }
  }
}

// scores dispatch (BK=64): compact lower-triangle (136/batch), quadratic-form
// bias in epilogue, fused column sums + P_un write. XCD-chunked.
__global__ __launch_bounds__(256, 2) void scores_k(
    const short* __restrict__ y, const short* __restrict__ xb,
    short* __restrict__ P, const float* __restrict__ u,
    const float* __restrict__ w, float* __restrict__ psum, int z0)
{
  __shared__ __align__(16) short lds[32768];
  const int nwg = (int)gridDim.x;
  int b = (int)blockIdx.x;
  b = (b & 7) * (nwg >> 3) + (b >> 3);
  const int z = b / 136;
  int idx = b - z * 136;
  int bm = 0;
  while ((bm + 1) * (bm + 2) / 2 <= idx) ++bm;
  int bn = idx - bm * (bm + 1) / 2;
  const long off = (long)(z0 + z) * 2048 * 1024;
  gemm_body64<short, 1>(lds, y + off, xb + off, P + (long)z * PSTR,
                        1024, 1024, 1024, 2048, 0.03125f, nullptr,
                        u + (long)(z0 + z) * 2048, w + (long)(z0 + z) * 2048,
                        psum, bn, bm, z);
}

// PV wrapper (grid 8x16xZ, BK=64): XCD-balanced (XCD k: bm=15-k then bm=k).
__global__ __launch_bounds__(256, 2) void pv_gemm(
    const short* __restrict__ A, const short* __restrict__ Bt, float* __restrict__ C,
    long sA, long sBt, long sC)
{
  __shared__ __align__(16) short lds[32768];
  const int k = (int)blockIdx.x;
  const int y = (int)blockIdx.y;
  const int bm = (y < 8) ? (15 - k) : k;
  const int bn = y & 7;
  const int bz = blockIdx.z;
  gemm_body64<float, 2>(lds, A + (long)bz * sA, Bt + (long)bz * sBt, C + (long)bz * sC,
                        2048, 2048, 8192, 1024, 1.f, nullptr, nullptr, nullptr,
                        nullptr, bn, bm, bz);
}

// ---------------- merged normalizer + V-scale ----------------
__global__ __launch_bounds__(256) void vscale_finv(
    const short* __restrict__ vt, const float* __restrict__ psum,
    short* __restrict__ vts, int b0)
{
  const int z = blockIdx.y;
  const int kc = blockIdx.x;
  const int k0 = kc * 32;
  __shared__ float finv[32];
  const int t = threadIdx.x;
  if (t < 32) {
    const int k = k0 + t;
    float D = 0.f;
    for (int ch = k >> 7; ch < 16; ++ch) D += psum[((long)z * 16 + ch) * 2048 + k];
    finv[t] = 1.f / D;
  }
  __syncthreads();
  const int kg = (t & 3) * 8;
  f32x4 fa = *(const f32x4*)(&finv[kg]);
  f32x4 fb = *(const f32x4*)(&finv[kg + 4]);
  const int dbase = t >> 2;
  const short* src = vt + (long)(b0 + z) * 2048 + k0 + kg;
  short* dst = vts + (long)z * 2048 + k0 + kg;
#pragma unroll 4
  for (int pass = 0; pass < 16; ++pass) {
    const long d = dbase + pass * 64;
    short8v v = *(const short8v*)(src + d * 8192);
    short8v o;
#pragma unroll
    for (int j = 0; j < 4; ++j) {
      o[j]     = (short)f2bf(bf2f(v[j]) * fa[j]);
      o[4 + j] = (short)f2bf(bf2f(v[4 + j]) * fb[j]);
    }
    *(short8v*)(dst + d * 8192) = o;
  }
}

// ---------------- host side ----------------
extern "C" void kernel_launch(void* const* d_in, const int* in_sizes, int n_in,
                              void* d_out, int out_size, void* d_ws, size_t ws_size,
                              hipStream_t stream) {
  const float* x  = (const float*)d_in[0];
  const float* Wq = (const float*)d_in[1];
  const float* bq = (const float*)d_in[2];
  const float* Wk = (const float*)d_in[3];
  const float* bk = (const float*)d_in[4];
  const float* Wv = (const float*)d_in[5];
  const float* bv = (const float*)d_in[6];
  float* out = (float*)d_out;

  const size_t SZ_XB  = 8192ull * 1024 * 2;        // xb / y bf16
  const size_t SZ_W   = 1024ull * 1024 * 2;        // wqb/wkb/wvt/Mt bf16
  const size_t SZ_VT  = 1024ull * 8192 * 2;
  const size_t N_PS   = 4ull * 16 * 2048;
  const size_t SZ_SM  = (N_PS + 8192 * 2 + 1024 * 2 + 64) * 4;
  const size_t SZ_P1  = 2048ull * 2048 * 2;        // one batch of P (bf16)

  char* p = (char*)d_ws;
  short* xb  = (short*)p; p += SZ_XB;
  short* yb  = (short*)p; p += SZ_XB;
  short* wqb = (short*)p; p += SZ_W;
  short* wkb = (short*)p; p += SZ_W;
  short* wvt = (short*)p; p += SZ_W;
  short* Mt  = (short*)p; p += SZ_W;
  short* vt  = (short*)p; p += SZ_VT;
  short* vts = (short*)p; p += SZ_VT;
  float* psum = (float*)p;
  float* u    = psum + N_PS;
  float* w    = u + 8192;
  float* g    = w + 8192;
  float* h    = g + 1024;
  float* cbuf = h + 1024;
  p += SZ_SM;
  size_t fixed = (size_t)(p - (char*)d_ws);
  int nbuf = (ws_size >= fixed + 4 * SZ_P1) ? 4 : 1;
  short* P = (short*)p;

  // 1) prologue: casts, Wv transpose, g/h/c
  pre_kernel<<<dim3(6657), dim3(256), 0, stream>>>(
      x, xb, Wq, Wk, Wv, wqb, wkb, wvt, bq, bk, g, h, cbuf);

  // 2) aux64: Vt projection (+bv) + Mt = Wk.Wq^T, all BK=64
  aux64<<<dim3(576), dim3(256), 0, stream>>>(wqb, wkb, Mt, xb, wvt, bv, vt);

  // 3) yuw: y = x.M (512 tiles, slice-owned) + u/w GEMV blocks, BK=64
  yuw<<<dim3(2560), dim3(256), 0, stream>>>(xb, Mt, yb, g, h, cbuf, u, w);

  for (int b0 = 0; b0 < 4; b0 += nbuf) {
    const int nz = nbuf;
    // 4) scores S = (y.x^T + u + w)/32 (+column sums, writes P_un bf16), BK=64
    scores_k<<<dim3(136 * nz), dim3(256), 0, stream>>>(
        yb, xb, P, u, w, psum, b0);
    // 5) per-column normalizer folded into V
    vscale_finv<<<dim3(64, nz), dim3(256), 0, stream>>>(vt, psum, vts, b0);
    // 6) attn = P_un @ Vscaled, K capped per q-tile, XCD-balanced, BK=64
    pv_gemm<<<dim3(8, 16, nz), dim3(256), 0, stream>>>(
        P, vts, out + (long)b0 * OSTR, PSTR, 2048L, OSTR);
  }
}

// Round 23
// 141.586 us; speedup vs baseline: 1.0636x; 1.0636x over previous
//
#include <hip/hip_runtime.h>

#define DEV __device__ __forceinline__

typedef float f32x4 __attribute__((ext_vector_type(4)));
typedef short short4v __attribute__((ext_vector_type(4)));
typedef short short8v __attribute__((ext_vector_type(8)));
typedef __bf16 bf16x8 __attribute__((ext_vector_type(8)));

#define PSTR  (2048L * 2048)
#define OSTR  (2048L * 1024)

DEV unsigned short f2bf(float f) {
  unsigned int u = __float_as_uint(f);
  u += 0x7fffu + ((u >> 16) & 1u);   // round-to-nearest-even
  return (unsigned short)(u >> 16);
}
DEV float bf2f(short s) {
  return __uint_as_float(((unsigned int)(unsigned short)s) << 16);
}

DEV void async16(void* lds, const void* g) {
  __builtin_amdgcn_global_load_lds((const __attribute__((address_space(1))) void*)g,
                                   (__attribute__((address_space(3))) void*)lds, 16, 0, 0);
}

DEV float wave_red(float v) {
#pragma unroll
  for (int o = 1; o < 64; o <<= 1) v += __shfl_xor(v, o);
  return v;
}

// ---------------- prologue: casts, Wv transpose, g/h/c ----------------
__global__ void pre_kernel(const float* __restrict__ x, short* __restrict__ xb,
                           const float* __restrict__ Wq, const float* __restrict__ Wk,
                           const float* __restrict__ Wv,
                           short* __restrict__ wqb, short* __restrict__ wkb,
                           short* __restrict__ wvt,
                           const float* __restrict__ bq, const float* __restrict__ bk,
                           float* __restrict__ g, float* __restrict__ h,
                           float* __restrict__ cbuf)
{
  __shared__ float t[32][33];
  const int b = blockIdx.x;
  const int tid = threadIdx.x;
  if (b < 4096) {                    // cast x -> bf16, 8 elems/thread
    long i = ((long)b * 256 + tid) * 8;
    f32x4 a = *(const f32x4*)(x + i);
    f32x4 c2 = *(const f32x4*)(x + i + 4);
    short8v o;
#pragma unroll
    for (int j = 0; j < 4; ++j) { o[j] = (short)f2bf(a[j]); o[4 + j] = (short)f2bf(c2[j]); }
    *(short8v*)(xb + i) = o;
  } else if (b < 5120) {             // straight cast Wq / Wk -> bf16
    int tb = b - 4096;
    const float* W = (tb < 512) ? Wq : Wk;
    short* Wo = (tb < 512) ? wqb : wkb;
    long i = ((long)(tb & 511) * 256 + tid) * 8;
    f32x4 a = *(const f32x4*)(W + i);
    f32x4 c2 = *(const f32x4*)(W + i + 4);
    short8v o;
#pragma unroll
    for (int j = 0; j < 4; ++j) { o[j] = (short)f2bf(a[j]); o[4 + j] = (short)f2bf(c2[j]); }
    *(short8v*)(Wo + i) = o;
  } else if (b < 6144) {             // transpose+cast one 32x32 tile of Wv
    int t2 = b - 5120;
    int n0 = (t2 & 31) * 32, k0 = (t2 >> 5) * 32;
    int tx = tid & 31, ty = tid >> 5;
#pragma unroll
    for (int r = 0; r < 32; r += 8) t[ty + r][tx] = Wv[(long)(k0 + ty + r) * 1024 + n0 + tx];
    __syncthreads();
#pragma unroll
    for (int r = 0; r < 32; r += 8)
      wvt[(long)(n0 + ty + r) * 1024 + k0 + tx] = (short)f2bf(t[tx][ty + r]);
  } else if (b < 6656) {             // g (256 blocks) then h (256 blocks)
    int local = b - 6144;
    const float* W = (local < 256) ? Wq : Wk;
    const float* bb = (local < 256) ? bk : bq;
    float* out = (local < 256) ? g : h;
    const int d = (local & 255) * 4 + (tid >> 6);
    const int lane = tid & 63;
    const float* row = W + (long)d * 1024 + lane * 16;
    const float* bp = bb + lane * 16;
    float s = 0.f;
#pragma unroll
    for (int q = 0; q < 4; ++q) {
      f32x4 wv = *(const f32x4*)(row + q * 4);
      f32x4 bv2 = *(const f32x4*)(bp + q * 4);
#pragma unroll
      for (int j = 0; j < 4; ++j) s += wv[j] * bv2[j];
    }
    s = wave_red(s);
    if (lane == 0) out[d] = s;
  } else {                           // c = bq . bk
    float s = 0.f;
#pragma unroll
    for (int q = 0; q < 4; ++q) s += bq[tid + q * 256] * bk[tid + q * 256];
    s = wave_red(s);
    __shared__ float red[4];
    if ((tid & 63) == 0) red[tid >> 6] = s;
    __syncthreads();
    if (tid == 0) cbuf[0] = red[0] + red[1] + red[2] + red[3];
  }
}

// ================= BK=64 body, 512 threads (8 waves, 2x4 wave grid) =================
// Same 128x128 tile / 64KB LDS / 2-barrier loop as R21, but 8 waves per block:
// per-block work per barrier interval unchanged (128 wave-MFMA), while
// 2 blocks/CU now give 16 waves/CU = 4 waves/SIMD (2x the wave slots).
// Staging: 16 chunks of 8 rows; wave w covers chunks {w, w+8}; lane l ->
// row l>>3, source col-slot (l&7)^(l>>3); reads XOR the same involution.
// MODE 0: bf16 out, LDS-bounce, optional row bias. MODE 1: scores. MODE 2: PV.
template <typename CT, int MODE>
DEV void gemm_body64(short* lds,
                     const short* A, const short* Bt, CT* C,
                     int K, int lda, int ldbt, int ldc,
                     float scale, const float* bias_m,
                     const float* u_vec, const float* w_vec,
                     float* ps_out, int bn, int bm, int bz)
{
  short* As0 = lds;
  short* As1 = lds + 8192;
  short* Bs0 = lds + 16384;
  short* Bs1 = lds + 24576;
  const int kend = (MODE == 2) ? min(K, (bm + 1) * 128) : K;

  const int tid = threadIdx.x;                     // 0..511
  const int wid = tid >> 6, lane = tid & 63;       // 8 waves
  const int wm = wid >> 2, wn = wid & 3;           // 2x4 wave grid
  const int lrow = lane >> 3;                      // row within 8-row chunk
  const int lcol = ((lane & 7) ^ lrow) * 8;        // inverse-swizzled source slot
  const int fr = lane & 15;
  const int fq = lane >> 4;

  const short* Ab = A + (long)(bm * 128 + lrow) * lda + lcol;
  const short* Bb = Bt + (long)(bn * 128 + lrow) * ldbt + lcol;

  f32x4 acc[4][2] = {};

  auto STAGE = [&](short* Asb, short* Bsb, int kk) {
#pragma unroll
    for (int j = 0; j < 2; ++j) {
      int chunk = j * 8 + wid;                     // 0..15 (8 rows each)
      async16(&Asb[chunk * 512], Ab + (long)chunk * 8 * lda + kk);
      async16(&Bsb[chunk * 512], Bb + (long)chunk * 8 * ldbt + kk);
    }
  };

  STAGE(As0, Bs0, 0);
  int cur = 0;
  for (int kk = 0; kk < kend; kk += 64) {
    const short* Ac = cur ? As1 : As0;
    const short* Bc = cur ? Bs1 : Bs0;
    if (kk + 64 < kend) {
      STAGE(cur ? As0 : As1, cur ? Bs0 : Bs1, kk + 64);
      asm volatile("s_waitcnt vmcnt(4)" ::: "memory");
    } else {
      asm volatile("s_waitcnt vmcnt(0)" ::: "memory");
    }
    __builtin_amdgcn_s_barrier();
    __builtin_amdgcn_sched_barrier(0);

#pragma unroll
    for (int s = 0; s < 2; ++s) {
      bf16x8 af[4], bf_[2];
#pragma unroll
      for (int i = 0; i < 4; ++i) {
        int row = wm * 64 + i * 16 + fr;
        af[i] = *(const bf16x8*)((const char*)Ac + row * 128 +
                                 (((s * 4 + fq) ^ (fr & 7)) * 16));
      }
#pragma unroll
      for (int j = 0; j < 2; ++j) {
        int row = wn * 32 + j * 16 + fr;
        bf_[j] = *(const bf16x8*)((const char*)Bc + row * 128 +
                                  (((s * 4 + fq) ^ (fr & 7)) * 16));
      }
#pragma unroll
      for (int i = 0; i < 4; ++i)
#pragma unroll
        for (int j = 0; j < 2; ++j)
          acc[i][j] = __builtin_amdgcn_mfma_f32_16x16x32_bf16(af[i], bf_[j], acc[i][j], 0, 0, 0);
    }
    __builtin_amdgcn_s_barrier();
    cur ^= 1;
  }

  const int rl0 = wm * 64 + fq * 4;        // local row base (i stride 16)
  const int cl0 = wn * 32 + fr;            // local col base (j stride 16)

  if constexpr (MODE == 2) {
#pragma unroll
    for (int i = 0; i < 4; ++i) {
#pragma unroll
      for (int r = 0; r < 4; ++r) {
        int row = bm * 128 + rl0 + i * 16 + r;
#pragma unroll
        for (int j = 0; j < 2; ++j) {
          int col = bn * 128 + cl0 + j * 16;
          C[(long)row * ldc + col] = acc[i][j][r] * scale;
        }
      }
    }
  } else {
    // -------- LDS-bounce epilogue (bf16 tile), pt spans As0|As1 --------
    short* pt = lds;                       // 16384 shorts = 128x128 tile
    if constexpr (MODE == 0) {
#pragma unroll
      for (int i = 0; i < 4; ++i) {
#pragma unroll
        for (int r = 0; r < 4; ++r) {
          int rl = rl0 + i * 16 + r;
          float bmv = bias_m ? bias_m[bm * 128 + rl] : 0.f;
#pragma unroll
          for (int j = 0; j < 2; ++j) {
            int cl = cl0 + j * 16;
            pt[rl * 128 + cl] = (short)f2bf(acc[i][j][r] * scale + bmv);
          }
        }
      }
    } else {
      float uu[4][4];
#pragma unroll
      for (int i = 0; i < 4; ++i)
#pragma unroll
        for (int r = 0; r < 4; ++r) uu[i][r] = u_vec[bm * 128 + rl0 + i * 16 + r];
#pragma unroll
      for (int j = 0; j < 2; ++j) {
        const int cl = cl0 + j * 16;
        const int col = bn * 128 + cl;
        const float wc = w_vec[col];
#pragma unroll
        for (int i = 0; i < 4; ++i)
#pragma unroll
          for (int r = 0; r < 4; ++r) {
            int rl = rl0 + i * 16 + r;
            int row = bm * 128 + rl;
            float e = (row >= col) ? __expf((acc[i][j][r] + uu[i][r] + wc) * scale) : 0.f;
            pt[rl * 128 + cl] = (short)f2bf(e);
          }
      }
    }
    __syncthreads();
    if constexpr (MODE == 1) {
      if (tid < 128) {
        float s = 0.f;
#pragma unroll 8
        for (int r2 = 0; r2 < 128; ++r2) s += bf2f(pt[r2 * 128 + tid]);
        ps_out[((long)bz * 16 + bm) * 2048 + bn * 128 + tid] = s;
      }
    }
    const long cbase = (long)bm * 128 * ldc + bn * 128;
#pragma unroll
    for (int p2 = 0; p2 < 4; ++p2) {
      int flat = p2 * 4096 + tid * 8;
      int rl = flat >> 7, cl = flat & 127;
      *(short8v*)((short*)C + cbase + (long)rl * ldc + cl) = *(const short8v*)(pt + flat);
    }
  }
}

// aux64 (576 = 8*72): per XCD k: 64 Vt tiles (slice-owned, bias bv over rows=d)
// + 8 M-tiles (Mt = Wk.Wq^T).
__global__ __launch_bounds__(512, 2) void aux64(
    const short* __restrict__ wqb, const short* __restrict__ wkb,
    short* __restrict__ Mt,
    const short* __restrict__ xb, const short* __restrict__ wvt,
    const float* __restrict__ bv, short* __restrict__ vt)
{
  __shared__ __align__(16) short lds[32768];
  int b = (int)blockIdx.x;
  const int k = b & 7;                           // XCD
  const int j = b >> 3;                          // [0,72)
  if (j < 64) {
    const int bn = k * 8 + (j & 7);              // Vt tile, slice-owned
    const int bm = j >> 3;
    gemm_body64<short, 0>(lds, wvt, xb, vt, 1024, 1024, 1024, 8192,
                          1.f, bv, nullptr, nullptr, nullptr, bn, bm, 0);
  } else {
    const int id = k * 8 + (j - 64);             // M tile
    gemm_body64<short, 0>(lds, wkb, wqb, Mt, 1024, 1024, 1024, 1024,
                          1.f, nullptr, nullptr, nullptr, nullptr, id & 7, id >> 3, 0);
  }
}

// yuw (1536 = 8*192): per XCD k: 64 ygemm tiles (slice-owned) + 128 u/w
// blocks (8 wave-rows each): u[s]=xb[s].g+c, w[s]=xb[s].h.
__global__ __launch_bounds__(512, 2) void yuw(
    const short* __restrict__ xb, const short* __restrict__ Mt,
    short* __restrict__ y,
    const float* __restrict__ g, const float* __restrict__ h,
    const float* __restrict__ cbuf,
    float* __restrict__ u, float* __restrict__ w)
{
  __shared__ __align__(16) short lds[32768];
  int b = (int)blockIdx.x;
  const int k = b & 7;                           // XCD
  const int j = b >> 3;                          // [0,192)
  if (j < 64) {
    const int bn = j >> 3;
    const int bm = k * 8 + (j & 7);              // slice-owned
    gemm_body64<short, 0>(lds, xb, Mt, y, 1024, 1024, 1024, 1024,
                          1.f, nullptr, nullptr, nullptr, nullptr, bn, bm, 0);
  } else {
    const int id = k * 128 + (j - 64);           // u/w: 8 rows (1 per wave)
    const int wv_ = threadIdx.x >> 6, lane = threadIdx.x & 63;
    const int s = id * 8 + wv_;
    const short* row = xb + (long)s * 1024 + lane * 16;
    const float* gp = g + lane * 16;
    const float* hp = h + lane * 16;
    short8v xa = *(const short8v*)(row);
    short8v xb2 = *(const short8v*)(row + 8);
    float du = 0.f, dw = 0.f;
#pragma unroll
    for (int q = 0; q < 2; ++q) {
      f32x4 ga = *(const f32x4*)(gp + q * 4);
      f32x4 gb = *(const f32x4*)(gp + 8 + q * 4);
      f32x4 ha = *(const f32x4*)(hp + q * 4);
      f32x4 hb = *(const f32x4*)(hp + 8 + q * 4);
#pragma unroll
      for (int i2 = 0; i2 < 4; ++i2) {
        float xv0 = bf2f(xa[q * 4 + i2]);
        float xv1 = bf2f(xb2[q * 4 + i2]);
        du += xv0 * ga[i2] + xv1 * gb[i2];
        dw += xv0 * ha[i2] + xv1 * hb[i2];
      }
    }
    du = wave_red(du);
    dw = wave_red(dw);
    if (lane == 0) { u[s] = du + cbuf[0]; w[s] = dw; }
  }
}

// scores dispatch: compact lower-triangle (136/batch), quadratic-form bias in
// epilogue, fused column sums + P_un write. XCD-chunked.
__global__ __launch_bounds__(512, 2) void scores_k(
    const short* __restrict__ y, const short* __restrict__ xb,
    short* __restrict__ P, const float* __restrict__ u,
    const float* __restrict__ w, float* __restrict__ psum, int z0)
{
  __shared__ __align__(16) short lds[32768];
  const int nwg = (int)gridDim.x;
  int b = (int)blockIdx.x;
  b = (b & 7) * (nwg >> 3) + (b >> 3);
  const int z = b / 136;
  int idx = b - z * 136;
  int bm = 0;
  while ((bm + 1) * (bm + 2) / 2 <= idx) ++bm;
  int bn = idx - bm * (bm + 1) / 2;
  const long off = (long)(z0 + z) * 2048 * 1024;
  gemm_body64<short, 1>(lds, y + off, xb + off, P + (long)z * PSTR,
                        1024, 1024, 1024, 2048, 0.03125f, nullptr,
                        u + (long)(z0 + z) * 2048, w + (long)(z0 + z) * 2048,
                        psum, bn, bm, z);
}

// PV wrapper (grid 8x16xZ): XCD-balanced (XCD k: bm=15-k then bm=k).
__global__ __launch_bounds__(512, 2) void pv_gemm(
    const short* __restrict__ A, const short* __restrict__ Bt, float* __restrict__ C,
    long sA, long sBt, long sC)
{
  __shared__ __align__(16) short lds[32768];
  const int k = (int)blockIdx.x;
  const int y = (int)blockIdx.y;
  const int bm = (y < 8) ? (15 - k) : k;
  const int bn = y & 7;
  const int bz = blockIdx.z;
  gemm_body64<float, 2>(lds, A + (long)bz * sA, Bt + (long)bz * sBt, C + (long)bz * sC,
                        2048, 2048, 8192, 1024, 1.f, nullptr, nullptr, nullptr,
                        nullptr, bn, bm, bz);
}

// ---------------- merged normalizer + V-scale ----------------
__global__ __launch_bounds__(256) void vscale_finv(
    const short* __restrict__ vt, const float* __restrict__ psum,
    short* __restrict__ vts, int b0)
{
  const int z = blockIdx.y;
  const int kc = blockIdx.x;
  const int k0 = kc * 32;
  __shared__ float finv[32];
  const int t = threadIdx.x;
  if (t < 32) {
    const int k = k0 + t;
    float D = 0.f;
    for (int ch = k >> 7; ch < 16; ++ch) D += psum[((long)z * 16 + ch) * 2048 + k];
    finv[t] = 1.f / D;
  }
  __syncthreads();
  const int kg = (t & 3) * 8;
  f32x4 fa = *(const f32x4*)(&finv[kg]);
  f32x4 fb = *(const f32x4*)(&finv[kg + 4]);
  const int dbase = t >> 2;
  const short* src = vt + (long)(b0 + z) * 2048 + k0 + kg;
  short* dst = vts + (long)z * 2048 + k0 + kg;
#pragma unroll 4
  for (int pass = 0; pass < 16; ++pass) {
    const long d = dbase + pass * 64;
    short8v v = *(const short8v*)(src + d * 8192);
    short8v o;
#pragma unroll
    for (int j = 0; j < 4; ++j) {
      o[j]     = (short)f2bf(bf2f(v[j]) * fa[j]);
      o[4 + j] = (short)f2bf(bf2f(v[4 + j]) * fb[j]);
    }
    *(short8v*)(dst + d * 8192) = o;
  }
}

// ---------------- host side ----------------
extern "C" void kernel_launch(void* const* d_in, const int* in_sizes, int n_in,
                              void* d_out, int out_size, void* d_ws, size_t ws_size,
                              hipStream_t stream) {
  const float* x  = (const float*)d_in[0];
  const float* Wq = (const float*)d_in[1];
  const float* bq = (const float*)d_in[2];
  const float* Wk = (const float*)d_in[3];
  const float* bk = (const float*)d_in[4];
  const float* Wv = (const float*)d_in[5];
  const float* bv = (const float*)d_in[6];
  float* out = (float*)d_out;

  const size_t SZ_XB  = 8192ull * 1024 * 2;        // xb / y bf16
  const size_t SZ_W   = 1024ull * 1024 * 2;        // wqb/wkb/wvt/Mt bf16
  const size_t SZ_VT  = 1024ull * 8192 * 2;
  const size_t N_PS   = 4ull * 16 * 2048;
  const size_t SZ_SM  = (N_PS + 8192 * 2 + 1024 * 2 + 64) * 4;
  const size_t SZ_P1  = 2048ull * 2048 * 2;        // one batch of P (bf16)

  char* p = (char*)d_ws;
  short* xb  = (short*)p; p += SZ_XB;
  short* yb  = (short*)p; p += SZ_XB;
  short* wqb = (short*)p; p += SZ_W;
  short* wkb = (short*)p; p += SZ_W;
  short* wvt = (short*)p; p += SZ_W;
  short* Mt  = (short*)p; p += SZ_W;
  short* vt  = (short*)p; p += SZ_VT;
  short* vts = (short*)p; p += SZ_VT;
  float* psum = (float*)p;
  float* u    = psum + N_PS;
  float* w    = u + 8192;
  float* g    = w + 8192;
  float* h    = g + 1024;
  float* cbuf = h + 1024;
  p += SZ_SM;
  size_t fixed = (size_t)(p - (char*)d_ws);
  int nbuf = (ws_size >= fixed + 4 * SZ_P1) ? 4 : 1;
  short* P = (short*)p;

  // 1) prologue: casts, Wv transpose, g/h/c
  pre_kernel<<<dim3(6657), dim3(256), 0, stream>>>(
      x, xb, Wq, Wk, Wv, wqb, wkb, wvt, bq, bk, g, h, cbuf);

  // 2) aux64: Vt projection (+bv) + Mt = Wk.Wq^T, 512-thread blocks
  aux64<<<dim3(576), dim3(512), 0, stream>>>(wqb, wkb, Mt, xb, wvt, bv, vt);

  // 3) yuw: y = x.M (512 tiles, slice-owned) + u/w GEMV blocks
  yuw<<<dim3(1536), dim3(512), 0, stream>>>(xb, Mt, yb, g, h, cbuf, u, w);

  for (int b0 = 0; b0 < 4; b0 += nbuf) {
    const int nz = nbuf;
    // 4) scores S = (y.x^T + u + w)/32 (+column sums, writes P_un bf16)
    scores_k<<<dim3(136 * nz), dim3(512), 0, stream>>>(
        yb, xb, P, u, w, psum, b0);
    // 5) per-column normalizer folded into V
    vscale_finv<<<dim3(64, nz), dim3(256), 0, stream>>>(vt, psum, vts, b0);
    // 6) attn = P_un @ Vscaled, K capped per q-tile, XCD-balanced
    pv_gemm<<<dim3(8, 16, nz), dim3(512), 0, stream>>>(
        P, vts, out + (long)b0 * OSTR, PSTR, 2048L, OSTR);
  }
}

// Round 24
// 140.036 us; speedup vs baseline: 1.0754x; 1.0111x over previous
//
#include <hip/hip_runtime.h>

#define DEV __device__ __forceinline__

typedef float f32x4 __attribute__((ext_vector_type(4)));
typedef short short4v __attribute__((ext_vector_type(4)));
typedef short short8v __attribute__((ext_vector_type(8)));
typedef __bf16 bf16x8 __attribute__((ext_vector_type(8)));

#define PSTR  (2048L * 2048)
#define OSTR  (2048L * 1024)

DEV unsigned short f2bf(float f) {
  unsigned int u = __float_as_uint(f);
  u += 0x7fffu + ((u >> 16) & 1u);   // round-to-nearest-even
  return (unsigned short)(u >> 16);
}
DEV float bf2f(short s) {
  return __uint_as_float(((unsigned int)(unsigned short)s) << 16);
}

DEV void async16(void* lds, const void* g) {
  __builtin_amdgcn_global_load_lds((const __attribute__((address_space(1))) void*)g,
                                   (__attribute__((address_space(3))) void*)lds, 16, 0, 0);
}

DEV float wave_red(float v) {
#pragma unroll
  for (int o = 1; o < 64; o <<= 1) v += __shfl_xor(v, o);
  return v;
}

// ---------------- prologue: casts, Wv transpose, g/h/c ----------------
__global__ void pre_kernel(const float* __restrict__ x, short* __restrict__ xb,
                           const float* __restrict__ Wq, const float* __restrict__ Wk,
                           const float* __restrict__ Wv,
                           short* __restrict__ wqb, short* __restrict__ wkb,
                           short* __restrict__ wvt,
                           const float* __restrict__ bq, const float* __restrict__ bk,
                           float* __restrict__ g, float* __restrict__ h,
                           float* __restrict__ cbuf)
{
  __shared__ float t[32][33];
  const int b = blockIdx.x;
  const int tid = threadIdx.x;
  if (b < 4096) {                    // cast x -> bf16, 8 elems/thread
    long i = ((long)b * 256 + tid) * 8;
    f32x4 a = *(const f32x4*)(x + i);
    f32x4 c2 = *(const f32x4*)(x + i + 4);
    short8v o;
#pragma unroll
    for (int j = 0; j < 4; ++j) { o[j] = (short)f2bf(a[j]); o[4 + j] = (short)f2bf(c2[j]); }
    *(short8v*)(xb + i) = o;
  } else if (b < 5120) {             // straight cast Wq / Wk -> bf16
    int tb = b - 4096;
    const float* W = (tb < 512) ? Wq : Wk;
    short* Wo = (tb < 512) ? wqb : wkb;
    long i = ((long)(tb & 511) * 256 + tid) * 8;
    f32x4 a = *(const f32x4*)(W + i);
    f32x4 c2 = *(const f32x4*)(W + i + 4);
    short8v o;
#pragma unroll
    for (int j = 0; j < 4; ++j) { o[j] = (short)f2bf(a[j]); o[4 + j] = (short)f2bf(c2[j]); }
    *(short8v*)(Wo + i) = o;
  } else if (b < 6144) {             // transpose+cast one 32x32 tile of Wv
    int t2 = b - 5120;
    int n0 = (t2 & 31) * 32, k0 = (t2 >> 5) * 32;
    int tx = tid & 31, ty = tid >> 5;
#pragma unroll
    for (int r = 0; r < 32; r += 8) t[ty + r][tx] = Wv[(long)(k0 + ty + r) * 1024 + n0 + tx];
    __syncthreads();
#pragma unroll
    for (int r = 0; r < 32; r += 8)
      wvt[(long)(n0 + ty + r) * 1024 + k0 + tx] = (short)f2bf(t[tx][ty + r]);
  } else if (b < 6656) {             // g (256 blocks) then h (256 blocks)
    int local = b - 6144;
    const float* W = (local < 256) ? Wq : Wk;
    const float* bb = (local < 256) ? bk : bq;
    float* out = (local < 256) ? g : h;
    const int d = (local & 255) * 4 + (tid >> 6);
    const int lane = tid & 63;
    const float* row = W + (long)d * 1024 + lane * 16;
    const float* bp = bb + lane * 16;
    float s = 0.f;
#pragma unroll
    for (int q = 0; q < 4; ++q) {
      f32x4 wv = *(const f32x4*)(row + q * 4);
      f32x4 bv2 = *(const f32x4*)(bp + q * 4);
#pragma unroll
      for (int j = 0; j < 4; ++j) s += wv[j] * bv2[j];
    }
    s = wave_red(s);
    if (lane == 0) out[d] = s;
  } else {                           // c = bq . bk
    float s = 0.f;
#pragma unroll
    for (int q = 0; q < 4; ++q) s += bq[tid + q * 256] * bk[tid + q * 256];
    s = wave_red(s);
    __shared__ float red[4];
    if ((tid & 63) == 0) red[tid >> 6] = s;
    __syncthreads();
    if (tid == 0) cbuf[0] = red[0] + red[1] + red[2] + red[3];
  }
}

// ================= BK=64 body, 512 threads (8 waves, 2x4 wave grid) =================
// 128x128 tile, 64KB LDS (As0|As1|Bs0|Bs1 x 8192 shorts), 2-barrier loop,
// counted vmcnt(4). 2 blocks/CU x 8 waves = 4 waves/SIMD.
// Staging: 16 chunks of 8 rows; wave w covers chunks {w, w+8}; lane l ->
// row l>>3, source col-slot (l&7)^(l>>3); reads XOR the same involution.
// MODE 0: bf16 out, LDS-bounce, optional row bias. MODE 1: scores (P_un +
// in-register column sums: csum accumulated at write time, fq-shfl reduce,
// wm-halves combined via the dead Bs region). MODE 2: PV (K cap, f32 out).
template <typename CT, int MODE>
DEV void gemm_body64(short* lds,
                     const short* A, const short* Bt, CT* C,
                     int K, int lda, int ldbt, int ldc,
                     float scale, const float* bias_m,
                     const float* u_vec, const float* w_vec,
                     float* ps_out, int bn, int bm, int bz)
{
  short* As0 = lds;
  short* As1 = lds + 8192;
  short* Bs0 = lds + 16384;
  short* Bs1 = lds + 24576;
  const int kend = (MODE == 2) ? min(K, (bm + 1) * 128) : K;

  const int tid = threadIdx.x;                     // 0..511
  const int wid = tid >> 6, lane = tid & 63;       // 8 waves
  const int wm = wid >> 2, wn = wid & 3;           // 2x4 wave grid
  const int lrow = lane >> 3;                      // row within 8-row chunk
  const int lcol = ((lane & 7) ^ lrow) * 8;        // inverse-swizzled source slot
  const int fr = lane & 15;
  const int fq = lane >> 4;

  const short* Ab = A + (long)(bm * 128 + lrow) * lda + lcol;
  const short* Bb = Bt + (long)(bn * 128 + lrow) * ldbt + lcol;

  f32x4 acc[4][2] = {};

  auto STAGE = [&](short* Asb, short* Bsb, int kk) {
#pragma unroll
    for (int j = 0; j < 2; ++j) {
      int chunk = j * 8 + wid;                     // 0..15 (8 rows each)
      async16(&Asb[chunk * 512], Ab + (long)chunk * 8 * lda + kk);
      async16(&Bsb[chunk * 512], Bb + (long)chunk * 8 * ldbt + kk);
    }
  };

  STAGE(As0, Bs0, 0);
  int cur = 0;
  for (int kk = 0; kk < kend; kk += 64) {
    const short* Ac = cur ? As1 : As0;
    const short* Bc = cur ? Bs1 : Bs0;
    if (kk + 64 < kend) {
      STAGE(cur ? As0 : As1, cur ? Bs0 : Bs1, kk + 64);
      asm volatile("s_waitcnt vmcnt(4)" ::: "memory");
    } else {
      asm volatile("s_waitcnt vmcnt(0)" ::: "memory");
    }
    __builtin_amdgcn_s_barrier();
    __builtin_amdgcn_sched_barrier(0);

#pragma unroll
    for (int s = 0; s < 2; ++s) {
      bf16x8 af[4], bf_[2];
#pragma unroll
      for (int i = 0; i < 4; ++i) {
        int row = wm * 64 + i * 16 + fr;
        af[i] = *(const bf16x8*)((const char*)Ac + row * 128 +
                                 (((s * 4 + fq) ^ (fr & 7)) * 16));
      }
#pragma unroll
      for (int j = 0; j < 2; ++j) {
        int row = wn * 32 + j * 16 + fr;
        bf_[j] = *(const bf16x8*)((const char*)Bc + row * 128 +
                                  (((s * 4 + fq) ^ (fr & 7)) * 16));
      }
#pragma unroll
      for (int i = 0; i < 4; ++i)
#pragma unroll
        for (int j = 0; j < 2; ++j)
          acc[i][j] = __builtin_amdgcn_mfma_f32_16x16x32_bf16(af[i], bf_[j], acc[i][j], 0, 0, 0);
    }
    __builtin_amdgcn_s_barrier();
    cur ^= 1;
  }

  const int rl0 = wm * 64 + fq * 4;        // local row base (i stride 16)
  const int cl0 = wn * 32 + fr;            // local col base (j stride 16)

  if constexpr (MODE == 2) {
#pragma unroll
    for (int i = 0; i < 4; ++i) {
#pragma unroll
      for (int r = 0; r < 4; ++r) {
        int row = bm * 128 + rl0 + i * 16 + r;
#pragma unroll
        for (int j = 0; j < 2; ++j) {
          int col = bn * 128 + cl0 + j * 16;
          C[(long)row * ldc + col] = acc[i][j][r] * scale;
        }
      }
    }
  } else {
    // -------- LDS-bounce epilogue (bf16 tile), pt spans As0|As1 --------
    short* pt = lds;                       // 16384 shorts = 128x128 tile
    if constexpr (MODE == 0) {
#pragma unroll
      for (int i = 0; i < 4; ++i) {
#pragma unroll
        for (int r = 0; r < 4; ++r) {
          int rl = rl0 + i * 16 + r;
          float bmv = bias_m ? bias_m[bm * 128 + rl] : 0.f;
#pragma unroll
          for (int j = 0; j < 2; ++j) {
            int cl = cl0 + j * 16;
            pt[rl * 128 + cl] = (short)f2bf(acc[i][j][r] * scale + bmv);
          }
        }
      }
      __syncthreads();
    } else {
      float uu[4][4];
#pragma unroll
      for (int i = 0; i < 4; ++i)
#pragma unroll
        for (int r = 0; r < 4; ++r) uu[i][r] = u_vec[bm * 128 + rl0 + i * 16 + r];
      float csum[2] = {0.f, 0.f};
#pragma unroll
      for (int j = 0; j < 2; ++j) {
        const int cl = cl0 + j * 16;
        const int col = bn * 128 + cl;
        const float wc = w_vec[col];
#pragma unroll
        for (int i = 0; i < 4; ++i)
#pragma unroll
          for (int r = 0; r < 4; ++r) {
            int rl = rl0 + i * 16 + r;
            int row = bm * 128 + rl;
            float e = (row >= col) ? __expf((acc[i][j][r] + uu[i][r] + wc) * scale) : 0.f;
            csum[j] += e;
            pt[rl * 128 + cl] = (short)f2bf(e);
          }
        csum[j] += __shfl_xor(csum[j], 16);    // reduce over the 4 fq lanes
        csum[j] += __shfl_xor(csum[j], 32);
      }
      // combine the two wm-halves through the dead Bs region
      float* sred = (float*)Bs0;               // [2][128] floats
      if (fq == 0) {
        sred[wm * 128 + cl0]      = csum[0];
        sred[wm * 128 + cl0 + 16] = csum[1];
      }
      __syncthreads();
      if (tid < 128)
        ps_out[((long)bz * 16 + bm) * 2048 + bn * 128 + tid] = sred[tid] + sred[128 + tid];
    }
    // coalesced global write: 4 passes x short8v (512 threads)
    const long cbase = (long)bm * 128 * ldc + bn * 128;
#pragma unroll
    for (int p2 = 0; p2 < 4; ++p2) {
      int flat = p2 * 4096 + tid * 8;
      int rl = flat >> 7, cl = flat & 127;
      *(short8v*)((short*)C + cbase + (long)rl * ldc + cl) = *(const short8v*)(pt + flat);
    }
  }
}

// aux64 (576 = 8*72): per XCD k: 64 Vt tiles (slice-owned, bias bv over rows=d)
// + 8 M-tiles (Mt = Wk.Wq^T).
__global__ __launch_bounds__(512, 2) void aux64(
    const short* __restrict__ wqb, const short* __restrict__ wkb,
    short* __restrict__ Mt,
    const short* __restrict__ xb, const short* __restrict__ wvt,
    const float* __restrict__ bv, short* __restrict__ vt)
{
  __shared__ __align__(16) short lds[32768];
  int b = (int)blockIdx.x;
  const int k = b & 7;                           // XCD
  const int j = b >> 3;                          // [0,72)
  if (j < 64) {
    const int bn = k * 8 + (j & 7);              // Vt tile, slice-owned
    const int bm = j >> 3;
    gemm_body64<short, 0>(lds, wvt, xb, vt, 1024, 1024, 1024, 8192,
                          1.f, bv, nullptr, nullptr, nullptr, bn, bm, 0);
  } else {
    const int id = k * 8 + (j - 64);             // M tile
    gemm_body64<short, 0>(lds, wkb, wqb, Mt, 1024, 1024, 1024, 1024,
                          1.f, nullptr, nullptr, nullptr, nullptr, id & 7, id >> 3, 0);
  }
}

// yuw (1536 = 8*192): per XCD k: 64 ygemm tiles (slice-owned) + 128 u/w
// blocks (8 wave-rows each): u[s]=xb[s].g+c, w[s]=xb[s].h.
__global__ __launch_bounds__(512, 2) void yuw(
    const short* __restrict__ xb, const short* __restrict__ Mt,
    short* __restrict__ y,
    const float* __restrict__ g, const float* __restrict__ h,
    const float* __restrict__ cbuf,
    float* __restrict__ u, float* __restrict__ w)
{
  __shared__ __align__(16) short lds[32768];
  int b = (int)blockIdx.x;
  const int k = b & 7;                           // XCD
  const int j = b >> 3;                          // [0,192)
  if (j < 64) {
    const int bn = j >> 3;
    const int bm = k * 8 + (j & 7);              // slice-owned
    gemm_body64<short, 0>(lds, xb, Mt, y, 1024, 1024, 1024, 1024,
                          1.f, nullptr, nullptr, nullptr, nullptr, bn, bm, 0);
  } else {
    const int id = k * 128 + (j - 64);           // u/w: 8 rows (1 per wave)
    const int wv_ = threadIdx.x >> 6, lane = threadIdx.x & 63;
    const int s = id * 8 + wv_;
    const short* row = xb + (long)s * 1024 + lane * 16;
    const float* gp = g + lane * 16;
    const float* hp = h + lane * 16;
    short8v xa = *(const short8v*)(row);
    short8v xb2 = *(const short8v*)(row + 8);
    float du = 0.f, dw = 0.f;
#pragma unroll
    for (int q = 0; q < 2; ++q) {
      f32x4 ga = *(const f32x4*)(gp + q * 4);
      f32x4 gb = *(const f32x4*)(gp + 8 + q * 4);
      f32x4 ha = *(const f32x4*)(hp + q * 4);
      f32x4 hb = *(const f32x4*)(hp + 8 + q * 4);
#pragma unroll
      for (int i2 = 0; i2 < 4; ++i2) {
        float xv0 = bf2f(xa[q * 4 + i2]);
        float xv1 = bf2f(xb2[q * 4 + i2]);
        du += xv0 * ga[i2] + xv1 * gb[i2];
        dw += xv0 * ha[i2] + xv1 * hb[i2];
      }
    }
    du = wave_red(du);
    dw = wave_red(dw);
    if (lane == 0) { u[s] = du + cbuf[0]; w[s] = dw; }
  }
}

// scores dispatch: compact lower-triangle (136/batch), quadratic-form bias in
// epilogue, fused in-register column sums + P_un write. XCD-chunked.
__global__ __launch_bounds__(512, 2) void scores_k(
    const short* __restrict__ y, const short* __restrict__ xb,
    short* __restrict__ P, const float* __restrict__ u,
    const float* __restrict__ w, float* __restrict__ psum, int z0)
{
  __shared__ __align__(16) short lds[32768];
  const int nwg = (int)gridDim.x;
  int b = (int)blockIdx.x;
  b = (b & 7) * (nwg >> 3) + (b >> 3);
  const int z = b / 136;
  int idx = b - z * 136;
  int bm = 0;
  while ((bm + 1) * (bm + 2) / 2 <= idx) ++bm;
  int bn = idx - bm * (bm + 1) / 2;
  const long off = (long)(z0 + z) * 2048 * 1024;
  gemm_body64<short, 1>(lds, y + off, xb + off, P + (long)z * PSTR,
                        1024, 1024, 1024, 2048, 0.03125f, nullptr,
                        u + (long)(z0 + z) * 2048, w + (long)(z0 + z) * 2048,
                        psum, bn, bm, z);
}

// PV wrapper (grid 8x16xZ): XCD-balanced (XCD k: bm=15-k then bm=k).
__global__ __launch_bounds__(512, 2) void pv_gemm(
    const short* __restrict__ A, const short* __restrict__ Bt, float* __restrict__ C,
    long sA, long sBt, long sC)
{
  __shared__ __align__(16) short lds[32768];
  const int k = (int)blockIdx.x;
  const int y = (int)blockIdx.y;
  const int bm = (y < 8) ? (15 - k) : k;
  const int bn = y & 7;
  const int bz = blockIdx.z;
  gemm_body64<float, 2>(lds, A + (long)bz * sA, Bt + (long)bz * sBt, C + (long)bz * sC,
                        2048, 2048, 8192, 1024, 1.f, nullptr, nullptr, nullptr,
                        nullptr, bn, bm, bz);
}

// ---------------- merged normalizer + V-scale ----------------
__global__ __launch_bounds__(256) void vscale_finv(
    const short* __restrict__ vt, const float* __restrict__ psum,
    short* __restrict__ vts, int b0)
{
  const int z = blockIdx.y;
  const int kc = blockIdx.x;
  const int k0 = kc * 32;
  __shared__ float finv[32];
  const int t = threadIdx.x;
  if (t < 32) {
    const int k = k0 + t;
    float D = 0.f;
    for (int ch = k >> 7; ch < 16; ++ch) D += psum[((long)z * 16 + ch) * 2048 + k];
    finv[t] = 1.f / D;
  }
  __syncthreads();
  const int kg = (t & 3) * 8;
  f32x4 fa = *(const f32x4*)(&finv[kg]);
  f32x4 fb = *(const f32x4*)(&finv[kg + 4]);
  const int dbase = t >> 2;
  const short* src = vt + (long)(b0 + z) * 2048 + k0 + kg;
  short* dst = vts + (long)z * 2048 + k0 + kg;
#pragma unroll 4
  for (int pass = 0; pass < 16; ++pass) {
    const long d = dbase + pass * 64;
    short8v v = *(const short8v*)(src + d * 8192);
    short8v o;
#pragma unroll
    for (int j = 0; j < 4; ++j) {
      o[j]     = (short)f2bf(bf2f(v[j]) * fa[j]);
      o[4 + j] = (short)f2bf(bf2f(v[4 + j]) * fb[j]);
    }
    *(short8v*)(dst + d * 8192) = o;
  }
}

// ---------------- host side ----------------
extern "C" void kernel_launch(void* const* d_in, const int* in_sizes, int n_in,
                              void* d_out, int out_size, void* d_ws, size_t ws_size,
                              hipStream_t stream) {
  const float* x  = (const float*)d_in[0];
  const float* Wq = (const float*)d_in[1];
  const float* bq = (const float*)d_in[2];
  const float* Wk = (const float*)d_in[3];
  const float* bk = (const float*)d_in[4];
  const float* Wv = (const float*)d_in[5];
  const float* bv = (const float*)d_in[6];
  float* out = (float*)d_out;

  const size_t SZ_XB  = 8192ull * 1024 * 2;        // xb / y bf16
  const size_t SZ_W   = 1024ull * 1024 * 2;        // wqb/wkb/wvt/Mt bf16
  const size_t SZ_VT  = 1024ull * 8192 * 2;
  const size_t N_PS   = 4ull * 16 * 2048;
  const size_t SZ_SM  = (N_PS + 8192 * 2 + 1024 * 2 + 64) * 4;
  const size_t SZ_P1  = 2048ull * 2048 * 2;        // one batch of P (bf16)

  char* p = (char*)d_ws;
  short* xb  = (short*)p; p += SZ_XB;
  short* yb  = (short*)p; p += SZ_XB;
  short* wqb = (short*)p; p += SZ_W;
  short* wkb = (short*)p; p += SZ_W;
  short* wvt = (short*)p; p += SZ_W;
  short* Mt  = (short*)p; p += SZ_W;
  short* vt  = (short*)p; p += SZ_VT;
  short* vts = (short*)p; p += SZ_VT;
  float* psum = (float*)p;
  float* u    = psum + N_PS;
  float* w    = u + 8192;
  float* g    = w + 8192;
  float* h    = g + 1024;
  float* cbuf = h + 1024;
  p += SZ_SM;
  size_t fixed = (size_t)(p - (char*)d_ws);
  int nbuf = (ws_size >= fixed + 4 * SZ_P1) ? 4 : 1;
  short* P = (short*)p;

  // 1) prologue: casts, Wv transpose, g/h/c
  pre_kernel<<<dim3(6657), dim3(256), 0, stream>>>(
      x, xb, Wq, Wk, Wv, wqb, wkb, wvt, bq, bk, g, h, cbuf);

  // 2) aux64: Vt projection (+bv) + Mt = Wk.Wq^T, 512-thread blocks
  aux64<<<dim3(576), dim3(512), 0, stream>>>(wqb, wkb, Mt, xb, wvt, bv, vt);

  // 3) yuw: y = x.M (512 tiles, slice-owned) + u/w GEMV blocks
  yuw<<<dim3(1536), dim3(512), 0, stream>>>(xb, Mt, yb, g, h, cbuf, u, w);

  for (int b0 = 0; b0 < 4; b0 += nbuf) {
    const int nz = nbuf;
    // 4) scores S = (y.x^T + u + w)/32 (+in-register column sums, P_un bf16)
    scores_k<<<dim3(136 * nz), dim3(512), 0, stream>>>(
        yb, xb, P, u, w, psum, b0);
    // 5) per-column normalizer folded into V
    vscale_finv<<<dim3(64, nz), dim3(256), 0, stream>>>(vt, psum, vts, b0);
    // 6) attn = P_un @ Vscaled, K capped per q-tile, XCD-balanced
    pv_gemm<<<dim3(8, 16, nz), dim3(512), 0, stream>>>(
        P, vts, out + (long)b0 * OSTR, PSTR, 2048L, OSTR);
  }
}